// Round 5
// baseline (210.419 us; speedup 1.0000x reference)
//
#include <hip/hip_runtime.h>
#include <stdint.h>

#define NW   2048
#define OBS  512
#define HS   512
#define HS2  512
#define HM   256
#define CTX  128
#define ACT  18
#define RPB  4      // rows per block
#define T    512    // threads per block

#define K2LE 2.8853900817779268f   // 2*log2(e)

// ws layout (floats)
#define W1T_OFF   0                      // [512][512]  W1T[k][c]
#define WCT_OFF   262144                 // [256][128]  WcT[m][c]
#define W2T_OFF   294912                 // [768][512]  W2T[k][c]
#define WHHQ_OFF  688128                 // [256][256] float4 (Wr,Wz,Wn,0)[m][j]

#if __has_builtin(__builtin_amdgcn_exp2f)
#define EXP2F(x) __builtin_amdgcn_exp2f(x)
#else
#define EXP2F(x) exp2f(x)
#endif
#if __has_builtin(__builtin_amdgcn_rcpf)
#define RCPF(x) __builtin_amdgcn_rcpf(x)
#else
#define RCPF(x) (1.0f/(x))
#endif

// ---------------- threefry2x32 (key = (0,42)), 20 rounds ----------------
#define TFR(x0, x1, R) { x0 += x1; x1 = (x1 << R) | (x1 >> (32 - R)); x1 ^= x0; }

__device__ __forceinline__ void threefry_0_42(uint32_t x0, uint32_t x1,
                                              uint32_t& o0, uint32_t& o1) {
    const uint32_t ks0 = 0u;
    const uint32_t ks1 = 42u;
    const uint32_t ks2 = 0x1BD11BDAu ^ ks0 ^ ks1;
    x0 += ks0; x1 += ks1;
    TFR(x0, x1, 13) TFR(x0, x1, 15) TFR(x0, x1, 26) TFR(x0, x1, 6)
    x0 += ks1; x1 += ks2 + 1u;
    TFR(x0, x1, 17) TFR(x0, x1, 29) TFR(x0, x1, 16) TFR(x0, x1, 24)
    x0 += ks2; x1 += ks0 + 2u;
    TFR(x0, x1, 13) TFR(x0, x1, 15) TFR(x0, x1, 26) TFR(x0, x1, 6)
    x0 += ks0; x1 += ks1 + 3u;
    TFR(x0, x1, 17) TFR(x0, x1, 29) TFR(x0, x1, 16) TFR(x0, x1, 24)
    x0 += ks1; x1 += ks2 + 4u;
    TFR(x0, x1, 13) TFR(x0, x1, 15) TFR(x0, x1, 26) TFR(x0, x1, 6)
    x0 += ks2; x1 += ks0 + 5u;
    o0 = x0; o1 = x1;
}

// jax_threefry_partitionable scheme (verified round 2): counter=(0,n), out0^out1
__device__ __forceinline__ float gumbel_ra(int row, int a) {
    uint32_t n = (uint32_t)(row * ACT + a);
    uint32_t o0, o1;
    threefry_0_42(0u, n, o0, o1);
    uint32_t bits = o0 ^ o1;
    uint32_t fb = (bits >> 9) | 0x3F800000u;
    float f = __uint_as_float(fb) - 1.0f;
    const float tiny = 1.17549435e-38f;
    float u = (f < tiny) ? tiny : f;
    return -logf(-logf(u));
}

__device__ __forceinline__ float fast_tanh(float x) {
    float e = __expf(2.0f * x);
    return 1.0f - 2.0f / (e + 1.0f);
}
__device__ __forceinline__ float fast_sig(float x) {
    return 1.0f / (1.0f + __expf(-x));
}

__device__ __forceinline__ void fma4(float4& a, float s, const float4 w) {
    a.x = fmaf(s, w.x, a.x); a.y = fmaf(s, w.y, a.y);
    a.z = fmaf(s, w.z, a.z); a.w = fmaf(s, w.w, a.w);
}

// ---- weight prep: transposes + GRU gate-pack into ws ----
__global__ __launch_bounds__(256) void transpose_weights(
    const float* __restrict__ W1, const float* __restrict__ Wc,
    const float* __restrict__ Whh, const float* __restrict__ W2,
    float* __restrict__ ws)
{
    __shared__ float t[3][32][33];
    const int tx = threadIdx.x & 31, ty = threadIdx.x >> 5;   // 32 x 8
    int b = blockIdx.x;
    if (b < 672) {
        const float* src; float* dst; int ld, off, R, it, jt;
        if (b < 256)      { src = W1;  dst = ws + W1T_OFF;  ld = 512; off = 0; it = b >> 4; jt = b & 15; R = 512; }
        else if (b < 288) { int bb = b - 256; src = Wc;  dst = ws + WCT_OFF;  ld = 257; off = 1; it = bb >> 3; jt = bb & 7;  R = 128; }
        else              { int bb = b - 288; src = W2;  dst = ws + W2T_OFF;  ld = 768; off = 0; it = bb / 24; jt = bb % 24; R = 512; }
        const int i0 = it * 32, j0 = jt * 32;
        #pragma unroll
        for (int q = 0; q < 4; ++q)
            t[0][ty + 8 * q][tx] = src[(i0 + ty + 8 * q) * ld + off + j0 + tx];
        __syncthreads();
        #pragma unroll
        for (int q = 0; q < 4; ++q)
            dst[(j0 + ty + 8 * q) * R + i0 + tx] = t[0][tx][ty + 8 * q];
    } else {
        // WhhQ: 64 blocks, tile (mt, jt) of 32x32
        int bb = b - 672;
        const int mt = bb >> 3, jt = bb & 7;
        const int m0 = mt * 32, j0 = jt * 32;
        #pragma unroll
        for (int g = 0; g < 3; ++g)
            #pragma unroll
            for (int q = 0; q < 4; ++q)
                t[g][ty + 8 * q][tx] = Whh[(g * HM + j0 + ty + 8 * q) * HM + m0 + tx];
        __syncthreads();
        float4* dst = (float4*)(ws + WHHQ_OFF);
        #pragma unroll
        for (int q = 0; q < 4; ++q) {
            int ml = ty + 8 * q, jl = tx;
            dst[(size_t)(m0 + ml) * HM + j0 + jl] =
                make_float4(t[0][jl][ml], t[1][jl][ml], t[2][jl][ml], 0.0f);
        }
    }
}

__global__ __launch_bounds__(T, 4) void iamgru_policy_kernel(
    const float* __restrict__ obs,   const float* __restrict__ hmem,
    const float* __restrict__ b1,
    const float* __restrict__ Wc,    const float* __restrict__ bc,
    const float* __restrict__ Wa,    const float* __restrict__ ba,
    const float* __restrict__ W_ih,  const float* __restrict__ b_ih,
    const float* __restrict__ b_hh,  const float* __restrict__ b2,
    const float* __restrict__ Wact,  const float* __restrict__ bact,
    const float* __restrict__ Wcrit, const float* __restrict__ bcrit,
    const float* __restrict__ ws,
    float* __restrict__ out)
{
    __shared__ float s_obs[RPB][OBS];     // 8 KB
    __shared__ float s_h[RPB][HM];        // 4 KB
    __shared__ float s_feat[RPB][HS];     // 8 KB
    __shared__ float s_hterm[RPB][CTX];   // 2 KB (pre-scaled by 2*log2e)
    __shared__ float s_buf[RPB][HS];      // 8 KB (stage-2 partials, alog, out2)
    __shared__ float s_wc0[CTX];          // pre-scaled by 2*log2e
    __shared__ float s_wa2[CTX];          // 2*Wa
    __shared__ float s_x[RPB];

    const int tid  = threadIdx.x;
    const int row0 = blockIdx.x * RPB;

    // ---- stage 0: stage obs + h into LDS (coalesced) ----
    for (int i = tid; i < RPB * OBS; i += T) {
        int r = i >> 9, o = i & (OBS - 1);
        s_obs[r][o] = obs[(row0 + r) * OBS + o];
    }
    for (int i = tid; i < RPB * HM; i += T) {
        int r = i >> 8, m = i & (HM - 1);
        s_h[r][m] = hmem[(row0 + r) * HM + m];
    }
    if (tid < CTX) {
        s_wc0[tid] = K2LE * Wc[tid * (HM + 1)];
        s_wa2[tid] = 2.0f * Wa[tid];
    }
    __syncthreads();

    // ---- stage 1: feat = relu(obs @ W1^T + b1) ----
    // thread = (kg in-wave pair, c4 col-quad, rq row-pair); shfl reduce over kg
    {
        const int kg = tid & 1;
        const int c4 = (tid >> 1) & 127;
        const int rq = tid >> 8;
        const int r0 = rq * 2, r1 = r0 + 1;
        const float4* __restrict__ W14 = (const float4*)(ws + W1T_OFF); // [512][128]
        float4 a0 = {0,0,0,0}, a1 = {0,0,0,0};
        const int kbase = kg * 256;
        #pragma unroll 2
        for (int q = 0; q < 64; ++q) {
            const int k = kbase + q * 4;
            float4 w0 = W14[(size_t)(k + 0) * 128 + c4];
            float4 w1 = W14[(size_t)(k + 1) * 128 + c4];
            float4 w2 = W14[(size_t)(k + 2) * 128 + c4];
            float4 w3 = W14[(size_t)(k + 3) * 128 + c4];
            float4 o0 = *(const float4*)&s_obs[r0][k];
            float4 o1 = *(const float4*)&s_obs[r1][k];
            fma4(a0, o0.x, w0); fma4(a0, o0.y, w1); fma4(a0, o0.z, w2); fma4(a0, o0.w, w3);
            fma4(a1, o1.x, w0); fma4(a1, o1.y, w1); fma4(a1, o1.z, w2); fma4(a1, o1.w, w3);
        }
        a0.x += __shfl_xor(a0.x, 1); a0.y += __shfl_xor(a0.y, 1);
        a0.z += __shfl_xor(a0.z, 1); a0.w += __shfl_xor(a0.w, 1);
        a1.x += __shfl_xor(a1.x, 1); a1.y += __shfl_xor(a1.y, 1);
        a1.z += __shfl_xor(a1.z, 1); a1.w += __shfl_xor(a1.w, 1);
        if (kg == 0) {
            float4 bb = *(const float4*)&b1[c4 * 4];
            float4 v0, v1;
            v0.x = fmaxf(a0.x + bb.x, 0.f); v0.y = fmaxf(a0.y + bb.y, 0.f);
            v0.z = fmaxf(a0.z + bb.z, 0.f); v0.w = fmaxf(a0.w + bb.w, 0.f);
            v1.x = fmaxf(a1.x + bb.x, 0.f); v1.y = fmaxf(a1.y + bb.y, 0.f);
            v1.z = fmaxf(a1.z + bb.z, 0.f); v1.w = fmaxf(a1.w + bb.w, 0.f);
            *(float4*)&s_feat[r0][c4 * 4] = v0;
            *(float4*)&s_feat[r1][c4 * 4] = v1;
        }
    }

    // ---- stage 2: h_term partials; all threads; 4-way k-split over m ----
    {
        const int c = tid & (CTX - 1);
        const int g = tid >> 7;              // m-range [g*64, g*64+64)
        const float* WcT = ws + WCT_OFF;
        float acc[RPB] = {0.f, 0.f, 0.f, 0.f};
        const float* wp = &WcT[c];
        #pragma unroll 2
        for (int m4 = 0; m4 < 16; ++m4) {
            int m = g * 64 + m4 * 4;
            float4 h0 = *(const float4*)&s_h[0][m];
            float4 h1 = *(const float4*)&s_h[1][m];
            float4 h2 = *(const float4*)&s_h[2][m];
            float4 h3 = *(const float4*)&s_h[3][m];
            float w0 = wp[(m + 0) * CTX];
            float w1 = wp[(m + 1) * CTX];
            float w2 = wp[(m + 2) * CTX];
            float w3 = wp[(m + 3) * CTX];
            acc[0] = fmaf(h0.x, w0, acc[0]); acc[0] = fmaf(h0.y, w1, acc[0]);
            acc[0] = fmaf(h0.z, w2, acc[0]); acc[0] = fmaf(h0.w, w3, acc[0]);
            acc[1] = fmaf(h1.x, w0, acc[1]); acc[1] = fmaf(h1.y, w1, acc[1]);
            acc[1] = fmaf(h1.z, w2, acc[1]); acc[1] = fmaf(h1.w, w3, acc[1]);
            acc[2] = fmaf(h2.x, w0, acc[2]); acc[2] = fmaf(h2.y, w1, acc[2]);
            acc[2] = fmaf(h2.z, w2, acc[2]); acc[2] = fmaf(h2.w, w3, acc[2]);
            acc[3] = fmaf(h3.x, w0, acc[3]); acc[3] = fmaf(h3.y, w1, acc[3]);
            acc[3] = fmaf(h3.z, w2, acc[3]); acc[3] = fmaf(h3.w, w3, acc[3]);
        }
        #pragma unroll
        for (int r = 0; r < RPB; ++r) s_buf[r][g * CTX + c] = acc[r];
    }
    __syncthreads();
    if (tid < CTX) {
        #pragma unroll
        for (int r = 0; r < RPB; ++r)
            s_hterm[r][tid] = K2LE * (bc[tid] + s_buf[r][tid] + s_buf[r][CTX + tid]
                            + s_buf[r][2 * CTX + tid] + s_buf[r][3 * CTX + tid]);
    }
    __syncthreads();

    // ---- stage 3: alog[r][o] = ba + Swa - sum_c (2wa_c)/(1 + 2^(ob*wc0s + hts)) ----
    {
        const float ba0 = ba[0];
        const int o = tid;
        float ob[RPB], acc[RPB];
        #pragma unroll
        for (int r = 0; r < RPB; ++r) { ob[r] = s_obs[r][o]; acc[r] = 0.0f; }
        float swa = 0.f;
        for (int c = 0; c < CTX; c += 4) {
            float4 v = *(const float4*)&s_wa2[c];
            swa += v.x + v.y + v.z + v.w;
        }
        swa *= 0.5f;
        #define TANH_TERM(r, hv, comp) { \
            float t_ = fmaf(ob[r], wc.comp, hv.comp); \
            float rc_ = RCPF(EXP2F(t_) + 1.0f); \
            acc[r] = fmaf(wa.comp, rc_, acc[r]); }
        for (int c4 = 0; c4 < CTX / 4; ++c4) {
            float4 wc = *(const float4*)&s_wc0[c4 * 4];
            float4 wa = *(const float4*)&s_wa2[c4 * 4];
            float4 h0 = *(const float4*)&s_hterm[0][c4 * 4];
            float4 h1 = *(const float4*)&s_hterm[1][c4 * 4];
            float4 h2 = *(const float4*)&s_hterm[2][c4 * 4];
            float4 h3 = *(const float4*)&s_hterm[3][c4 * 4];
            TANH_TERM(0, h0, x) TANH_TERM(0, h0, y) TANH_TERM(0, h0, z) TANH_TERM(0, h0, w)
            TANH_TERM(1, h1, x) TANH_TERM(1, h1, y) TANH_TERM(1, h1, z) TANH_TERM(1, h1, w)
            TANH_TERM(2, h2, x) TANH_TERM(2, h2, y) TANH_TERM(2, h2, z) TANH_TERM(2, h2, w)
            TANH_TERM(3, h3, x) TANH_TERM(3, h3, y) TANH_TERM(3, h3, z) TANH_TERM(3, h3, w)
        }
        #pragma unroll
        for (int r = 0; r < RPB; ++r) s_buf[r][o] = ba0 + swa - acc[r];
    }
    __syncthreads();

    // ---- stage 4: softmax over o + dset -> x[r] (wave per row) ----
    {
        const int w = tid >> 6, lane = tid & 63;
        if (w < RPB) {
            const int r = w;
            float m = -1e30f;
            for (int o = lane; o < OBS; o += 64) m = fmaxf(m, s_buf[r][o]);
            #pragma unroll
            for (int d = 32; d >= 1; d >>= 1) m = fmaxf(m, __shfl_xor(m, d));
            float se = 0.0f, sw = 0.0f;
            for (int o = lane; o < OBS; o += 64) {
                float e = __expf(s_buf[r][o] - m);
                se += e; sw += e * s_obs[r][o];
            }
            #pragma unroll
            for (int d = 32; d >= 1; d >>= 1) { se += __shfl_xor(se, d); sw += __shfl_xor(sw, d); }
            if (lane == 0) s_x[r] = sw / se;
        }
    }
    __syncthreads();

    // ---- stage 5: GRU; thread=(j, row-half); gate-packed WhhQ float4 ----
    {
        const int j = tid & (HM - 1);
        const int half = tid >> 8;
        const int rbase = half * 2;
        const float4* __restrict__ Q = (const float4*)(ws + WHHQ_OFF); // [256][256]
        float accr[2], accz[2], accn[2];
        float bhr = b_hh[j], bhz = b_hh[HM + j], bhn = b_hh[2 * HM + j];
        accr[0] = accr[1] = bhr; accz[0] = accz[1] = bhz; accn[0] = accn[1] = bhn;
        #pragma unroll 2
        for (int m4 = 0; m4 < HM / 4; ++m4) {
            const int m = m4 * 4;
            float4 q0 = Q[(size_t)(m + 0) * HM + j];
            float4 q1 = Q[(size_t)(m + 1) * HM + j];
            float4 q2 = Q[(size_t)(m + 2) * HM + j];
            float4 q3 = Q[(size_t)(m + 3) * HM + j];
            float4 h0 = *(const float4*)&s_h[rbase][m];
            float4 h1 = *(const float4*)&s_h[rbase + 1][m];
            accr[0] = fmaf(h0.x, q0.x, accr[0]); accz[0] = fmaf(h0.x, q0.y, accz[0]); accn[0] = fmaf(h0.x, q0.z, accn[0]);
            accr[0] = fmaf(h0.y, q1.x, accr[0]); accz[0] = fmaf(h0.y, q1.y, accz[0]); accn[0] = fmaf(h0.y, q1.z, accn[0]);
            accr[0] = fmaf(h0.z, q2.x, accr[0]); accz[0] = fmaf(h0.z, q2.y, accz[0]); accn[0] = fmaf(h0.z, q2.z, accn[0]);
            accr[0] = fmaf(h0.w, q3.x, accr[0]); accz[0] = fmaf(h0.w, q3.y, accz[0]); accn[0] = fmaf(h0.w, q3.z, accn[0]);
            accr[1] = fmaf(h1.x, q0.x, accr[1]); accz[1] = fmaf(h1.x, q0.y, accz[1]); accn[1] = fmaf(h1.x, q0.z, accn[1]);
            accr[1] = fmaf(h1.y, q1.x, accr[1]); accz[1] = fmaf(h1.y, q1.y, accz[1]); accn[1] = fmaf(h1.y, q1.z, accn[1]);
            accr[1] = fmaf(h1.z, q2.x, accr[1]); accz[1] = fmaf(h1.z, q2.y, accz[1]); accn[1] = fmaf(h1.z, q2.z, accn[1]);
            accr[1] = fmaf(h1.w, q3.x, accr[1]); accz[1] = fmaf(h1.w, q3.y, accz[1]); accn[1] = fmaf(h1.w, q3.z, accn[1]);
        }
        float wih_r = W_ih[j], wih_z = W_ih[HM + j], wih_n = W_ih[2 * HM + j];
        float bih_r = b_ih[j], bih_z = b_ih[HM + j], bih_n = b_ih[2 * HM + j];
        float hnew[2];
        #pragma unroll
        for (int q = 0; q < 2; ++q) {
            const int r = rbase + q;
            float x  = s_x[r];
            float hp = s_h[r][j];
            float rg = fast_sig(fmaf(x, wih_r, bih_r) + accr[q]);
            float zg = fast_sig(fmaf(x, wih_z, bih_z) + accz[q]);
            float ng = fast_tanh(fmaf(x, wih_n, bih_n) + rg * accn[q]);
            hnew[q] = (1.0f - zg) * ng + zg * hp;
        }
        __syncthreads();                       // all hp reads done
        #pragma unroll
        for (int q = 0; q < 2; ++q) s_h[rbase + q][j] = hnew[q];
    }
    __syncthreads();

    // ---- stage 6: out2 = relu([feat, hnew] @ W2^T + b2); tiled like stage 1 ----
    {
        const int kg = tid & 1;
        const int c4 = (tid >> 1) & 127;
        const int rq = tid >> 8;
        const int r0 = rq * 2, r1 = r0 + 1;
        const float4* __restrict__ W24 = (const float4*)(ws + W2T_OFF); // [768][128]
        float4 a0 = {0,0,0,0}, a1 = {0,0,0,0};
        // loop A: k = kg*384 + q*4, both kg halves read s_feat
        #pragma unroll 2
        for (int q = 0; q < 32; ++q) {
            const int k = kg * 384 + q * 4;
            float4 w0 = W24[(size_t)(k + 0) * 128 + c4];
            float4 w1 = W24[(size_t)(k + 1) * 128 + c4];
            float4 w2 = W24[(size_t)(k + 2) * 128 + c4];
            float4 w3 = W24[(size_t)(k + 3) * 128 + c4];
            float4 o0 = *(const float4*)&s_feat[r0][k];
            float4 o1 = *(const float4*)&s_feat[r1][k];
            fma4(a0, o0.x, w0); fma4(a0, o0.y, w1); fma4(a0, o0.z, w2); fma4(a0, o0.w, w3);
            fma4(a1, o1.x, w0); fma4(a1, o1.y, w1); fma4(a1, o1.z, w2); fma4(a1, o1.w, w3);
        }
        // loop B: kg0 -> feat[128..383]; kg1 -> h[0..255] (per-lane LDS base)
        const float* actb0 = kg ? &s_h[r0][0] : &s_feat[r0][128];
        const float* actb1 = kg ? &s_h[r1][0] : &s_feat[r1][128];
        const int kwb = kg ? 512 : 128;
        #pragma unroll 2
        for (int q = 0; q < 64; ++q) {
            const int k = kwb + q * 4;
            float4 w0 = W24[(size_t)(k + 0) * 128 + c4];
            float4 w1 = W24[(size_t)(k + 1) * 128 + c4];
            float4 w2 = W24[(size_t)(k + 2) * 128 + c4];
            float4 w3 = W24[(size_t)(k + 3) * 128 + c4];
            float4 o0 = *(const float4*)&actb0[q * 4];
            float4 o1 = *(const float4*)&actb1[q * 4];
            fma4(a0, o0.x, w0); fma4(a0, o0.y, w1); fma4(a0, o0.z, w2); fma4(a0, o0.w, w3);
            fma4(a1, o1.x, w0); fma4(a1, o1.y, w1); fma4(a1, o1.z, w2); fma4(a1, o1.w, w3);
        }
        a0.x += __shfl_xor(a0.x, 1); a0.y += __shfl_xor(a0.y, 1);
        a0.z += __shfl_xor(a0.z, 1); a0.w += __shfl_xor(a0.w, 1);
        a1.x += __shfl_xor(a1.x, 1); a1.y += __shfl_xor(a1.y, 1);
        a1.z += __shfl_xor(a1.z, 1); a1.w += __shfl_xor(a1.w, 1);
        __syncthreads();   // alog reads (stage 4) done; safe to overwrite s_buf
        if (kg == 0) {
            float4 bb = *(const float4*)&b2[c4 * 4];
            float4 v0, v1;
            v0.x = fmaxf(a0.x + bb.x, 0.f); v0.y = fmaxf(a0.y + bb.y, 0.f);
            v0.z = fmaxf(a0.z + bb.z, 0.f); v0.w = fmaxf(a0.w + bb.w, 0.f);
            v1.x = fmaxf(a1.x + bb.x, 0.f); v1.y = fmaxf(a1.y + bb.y, 0.f);
            v1.z = fmaxf(a1.z + bb.z, 0.f); v1.w = fmaxf(a1.w + bb.w, 0.f);
            *(float4*)&s_buf[r0][c4 * 4] = v0;
            *(float4*)&s_buf[r1][c4 * 4] = v1;
        }
    }
    __syncthreads();

    // ---- stage 7: heads + categorical sampling ----
    {
        const int w = tid >> 6, lane = tid & 63;
        if (w < RPB) {
            const int r = w;
            const int grow = row0 + r;
            float4 x0 = *(const float4*)&s_buf[r][lane * 8];
            float4 x1 = *(const float4*)&s_buf[r][lane * 8 + 4];
            float la[ACT];
            #pragma unroll
            for (int a = 0; a < ACT; ++a) {
                const float4* wa4 = (const float4*)&Wact[a * HS2 + lane * 8];
                float4 w0 = wa4[0], w1 = wa4[1];
                float p = x0.x * w0.x + x0.y * w0.y + x0.z * w0.z + x0.w * w0.w
                        + x1.x * w1.x + x1.y * w1.y + x1.z * w1.z + x1.w * w1.w;
                #pragma unroll
                for (int d = 32; d >= 1; d >>= 1) p += __shfl_xor(p, d);
                la[a] = p + bact[a];
            }
            float g = (lane < ACT) ? gumbel_ra(grow, lane) : 0.0f;
            float best = -1e30f; int amax = 0;
            float mx = -1e30f;
            #pragma unroll
            for (int a = 0; a < ACT; ++a) {
                float g_ = __shfl(g, a);
                float y = la[a] + g_;
                if (y > best) { best = y; amax = a; }
                mx = fmaxf(mx, la[a]);
            }
            float se = 0.0f;
            #pragma unroll
            for (int a = 0; a < ACT; ++a) se += __expf(la[a] - mx);
            float lse = mx + logf(se);
            float lp = la[amax] - lse;
            if (lane == 0) {
                out[grow]          = (float)amax;
                out[2 * NW + grow] = lp;
            }
        } else {
            const int r = w - RPB;
            const int grow = row0 + r;
            float4 x0 = *(const float4*)&s_buf[r][lane * 8];
            float4 x1 = *(const float4*)&s_buf[r][lane * 8 + 4];
            const float4* wc4 = (const float4*)&Wcrit[lane * 8];
            float4 w0 = wc4[0], w1 = wc4[1];
            float p = x0.x * w0.x + x0.y * w0.y + x0.z * w0.z + x0.w * w0.w
                    + x1.x * w1.x + x1.y * w1.y + x1.z * w1.z + x1.w * w1.w;
            #pragma unroll
            for (int d = 32; d >= 1; d >>= 1) p += __shfl_xor(p, d);
            if (lane == 0) out[NW + grow] = p + bcrit[0];
        }
    }
}

extern "C" void kernel_launch(void* const* d_in, const int* in_sizes, int n_in,
                              void* d_out, int out_size, void* d_ws, size_t ws_size,
                              hipStream_t stream) {
    const float* obs   = (const float*)d_in[0];
    const float* hmem  = (const float*)d_in[1];
    const float* W1    = (const float*)d_in[2];
    const float* b1    = (const float*)d_in[3];
    const float* Wc    = (const float*)d_in[4];
    const float* bc    = (const float*)d_in[5];
    const float* Wa    = (const float*)d_in[6];
    const float* ba    = (const float*)d_in[7];
    const float* W_ih  = (const float*)d_in[8];
    const float* b_ih  = (const float*)d_in[9];
    const float* W_hh  = (const float*)d_in[10];
    const float* b_hh  = (const float*)d_in[11];
    const float* W2    = (const float*)d_in[12];
    const float* b2    = (const float*)d_in[13];
    const float* Wact  = (const float*)d_in[14];
    const float* bact  = (const float*)d_in[15];
    const float* Wcrit = (const float*)d_in[16];
    const float* bcrit = (const float*)d_in[17];
    float* ws = (float*)d_ws;

    transpose_weights<<<736, 256, 0, stream>>>(W1, Wc, W_hh, W2, ws);

    iamgru_policy_kernel<<<NW / RPB, T, 0, stream>>>(
        obs, hmem, b1, Wc, bc, Wa, ba, W_ih, b_ih, b_hh,
        b2, Wact, bact, Wcrit, bcrit, ws, (float*)d_out);
}

// Round 6
// 109.465 us; speedup vs baseline: 1.9222x; 1.9222x over previous
//
#include <hip/hip_runtime.h>
#include <stdint.h>

#define NW   2048
#define OBS  512
#define HS   512
#define HS2  512
#define HM   256
#define CTX  128
#define ACT  18
#define RPB  4      // rows per block
#define T    512    // threads per block

#define K2LE 2.8853900817779268f   // 2*log2(e)

// ws layout (floats)
#define W1T_OFF   0                      // [512][512]  W1T[k][c]
#define WCT_OFF   262144                 // [256][128]  WcT[m][c]
#define W2T_OFF   294912                 // [768][512]  W2T[k][c]
#define WHHQ_OFF  688128                 // [256][256] float4 (Wr,Wz,Wn,0)[m][j]

#if __has_builtin(__builtin_amdgcn_exp2f)
#define EXP2F(x) __builtin_amdgcn_exp2f(x)
#else
#define EXP2F(x) exp2f(x)
#endif
#if __has_builtin(__builtin_amdgcn_rcpf)
#define RCPF(x) __builtin_amdgcn_rcpf(x)
#else
#define RCPF(x) (1.0f/(x))
#endif

// ---------------- threefry2x32 (key = (0,42)), 20 rounds ----------------
#define TFR(x0, x1, R) { x0 += x1; x1 = (x1 << R) | (x1 >> (32 - R)); x1 ^= x0; }

__device__ __forceinline__ void threefry_0_42(uint32_t x0, uint32_t x1,
                                              uint32_t& o0, uint32_t& o1) {
    const uint32_t ks0 = 0u;
    const uint32_t ks1 = 42u;
    const uint32_t ks2 = 0x1BD11BDAu ^ ks0 ^ ks1;
    x0 += ks0; x1 += ks1;
    TFR(x0, x1, 13) TFR(x0, x1, 15) TFR(x0, x1, 26) TFR(x0, x1, 6)
    x0 += ks1; x1 += ks2 + 1u;
    TFR(x0, x1, 17) TFR(x0, x1, 29) TFR(x0, x1, 16) TFR(x0, x1, 24)
    x0 += ks2; x1 += ks0 + 2u;
    TFR(x0, x1, 13) TFR(x0, x1, 15) TFR(x0, x1, 26) TFR(x0, x1, 6)
    x0 += ks0; x1 += ks1 + 3u;
    TFR(x0, x1, 17) TFR(x0, x1, 29) TFR(x0, x1, 16) TFR(x0, x1, 24)
    x0 += ks1; x1 += ks2 + 4u;
    TFR(x0, x1, 13) TFR(x0, x1, 15) TFR(x0, x1, 26) TFR(x0, x1, 6)
    x0 += ks2; x1 += ks0 + 5u;
    o0 = x0; o1 = x1;
}

// jax_threefry_partitionable scheme (verified round 2): counter=(0,n), out0^out1
__device__ __forceinline__ float gumbel_ra(int row, int a) {
    uint32_t n = (uint32_t)(row * ACT + a);
    uint32_t o0, o1;
    threefry_0_42(0u, n, o0, o1);
    uint32_t bits = o0 ^ o1;
    uint32_t fb = (bits >> 9) | 0x3F800000u;
    float f = __uint_as_float(fb) - 1.0f;
    const float tiny = 1.17549435e-38f;
    float u = (f < tiny) ? tiny : f;
    return -logf(-logf(u));
}

__device__ __forceinline__ float fast_tanh(float x) {
    float e = __expf(2.0f * x);
    return 1.0f - 2.0f / (e + 1.0f);
}
__device__ __forceinline__ float fast_sig(float x) {
    return 1.0f / (1.0f + __expf(-x));
}

__device__ __forceinline__ void fma4(float4& a, float s, const float4 w) {
    a.x = fmaf(s, w.x, a.x); a.y = fmaf(s, w.y, a.y);
    a.z = fmaf(s, w.z, a.z); a.w = fmaf(s, w.w, a.w);
}

// ---- weight prep: transposes + GRU gate-pack into ws ----
__global__ __launch_bounds__(256) void transpose_weights(
    const float* __restrict__ W1, const float* __restrict__ Wc,
    const float* __restrict__ Whh, const float* __restrict__ W2,
    float* __restrict__ ws)
{
    __shared__ float t[3][32][33];
    const int tx = threadIdx.x & 31, ty = threadIdx.x >> 5;   // 32 x 8
    int b = blockIdx.x;
    if (b < 672) {
        const float* src; float* dst; int ld, off, R, it, jt;
        if (b < 256)      { src = W1;  dst = ws + W1T_OFF;  ld = 512; off = 0; it = b >> 4; jt = b & 15; R = 512; }
        else if (b < 288) { int bb = b - 256; src = Wc;  dst = ws + WCT_OFF;  ld = 257; off = 1; it = bb >> 3; jt = bb & 7;  R = 128; }
        else              { int bb = b - 288; src = W2;  dst = ws + W2T_OFF;  ld = 768; off = 0; it = bb / 24; jt = bb % 24; R = 512; }
        const int i0 = it * 32, j0 = jt * 32;
        #pragma unroll
        for (int q = 0; q < 4; ++q)
            t[0][ty + 8 * q][tx] = src[(i0 + ty + 8 * q) * ld + off + j0 + tx];
        __syncthreads();
        #pragma unroll
        for (int q = 0; q < 4; ++q)
            dst[(j0 + ty + 8 * q) * R + i0 + tx] = t[0][tx][ty + 8 * q];
    } else {
        // WhhQ: 64 blocks, tile (mt, jt) of 32x32
        int bb = b - 672;
        const int mt = bb >> 3, jt = bb & 7;
        const int m0 = mt * 32, j0 = jt * 32;
        #pragma unroll
        for (int g = 0; g < 3; ++g)
            #pragma unroll
            for (int q = 0; q < 4; ++q)
                t[g][ty + 8 * q][tx] = Whh[(g * HM + j0 + ty + 8 * q) * HM + m0 + tx];
        __syncthreads();
        float4* dst = (float4*)(ws + WHHQ_OFF);
        #pragma unroll
        for (int q = 0; q < 4; ++q) {
            int ml = ty + 8 * q, jl = tx;
            dst[(size_t)(m0 + ml) * HM + j0 + jl] =
                make_float4(t[0][jl][ml], t[1][jl][ml], t[2][jl][ml], 0.0f);
        }
    }
}

__global__ __launch_bounds__(T, 4) void iamgru_policy_kernel(
    const float* __restrict__ obs,   const float* __restrict__ hmem,
    const float* __restrict__ b1,
    const float* __restrict__ Wc,    const float* __restrict__ bc,
    const float* __restrict__ Wa,    const float* __restrict__ ba,
    const float* __restrict__ W_ih,  const float* __restrict__ b_ih,
    const float* __restrict__ b_hh,  const float* __restrict__ b2,
    const float* __restrict__ Wact,  const float* __restrict__ bact,
    const float* __restrict__ Wcrit, const float* __restrict__ bcrit,
    const float* __restrict__ ws,
    float* __restrict__ out)
{
    __shared__ float s_obs[RPB][OBS];     // 8 KB  (live: stage0..4)
    __shared__ float s_h[RPB][HM];        // 4 KB  (hp; hnew after stage 5)
    __shared__ float s_feat[RPB][HS];     // 8 KB  (feat; out2 after stage 6)
    __shared__ float s_hterm[RPB][CTX];   // 2 KB  (pre-scaled by 2*log2e)
    __shared__ float s_scr[8192];         // 32 KB scratch, lifetime-aliased:
                                          //   stage1/6 partials P4, stage2 partials+alog, stage5 partials GP
    __shared__ float s_wc0[CTX];          // pre-scaled by 2*log2e
    __shared__ float s_wa2[CTX];          // 2*Wa
    __shared__ float s_x[RPB];

    float (*s_buf)[HS] = (float (*)[HS])s_scr;   // [4][512] view
    float4* P4 = (float4*)s_scr;                 // [r][kg][c4] = ((r*4+kg)*128+c4)
    float*  GP = s_scr;                          // [mg][slot][j] = ((mg*12+slot)*256+j)

    const int tid  = threadIdx.x;
    const int row0 = blockIdx.x * RPB;

    // ---- stage 0: stage obs + h into LDS (coalesced) ----
    for (int i = tid; i < RPB * OBS; i += T) {
        int r = i >> 9, o = i & (OBS - 1);
        s_obs[r][o] = obs[(row0 + r) * OBS + o];
    }
    for (int i = tid; i < RPB * HM; i += T) {
        int r = i >> 8, m = i & (HM - 1);
        s_h[r][m] = hmem[(row0 + r) * HM + m];
    }
    if (tid < CTX) {
        s_wc0[tid] = K2LE * Wc[tid * (HM + 1)];
        s_wa2[tid] = 2.0f * Wa[tid];
    }
    __syncthreads();

    // ---- stage 1a: feat partial accum; thread = (kg wave-uniform, c4); 4 rows in regs ----
    {
        const int kg = tid >> 7;             // 0..3, wave-uniform
        const int c4 = tid & 127;
        const float4* __restrict__ W14 = (const float4*)(ws + W1T_OFF); // [512][128]
        float4 acc[RPB];
        #pragma unroll
        for (int r = 0; r < RPB; ++r) acc[r] = make_float4(0.f, 0.f, 0.f, 0.f);
        #pragma unroll 2
        for (int q = 0; q < 32; ++q) {
            const int k = kg * 128 + q * 4;
            float4 w0 = W14[(k + 0) * 128 + c4];
            float4 w1 = W14[(k + 1) * 128 + c4];
            float4 w2 = W14[(k + 2) * 128 + c4];
            float4 w3 = W14[(k + 3) * 128 + c4];
            #pragma unroll
            for (int r = 0; r < RPB; ++r) {
                float4 o = *(const float4*)&s_obs[r][k];   // wave-uniform broadcast
                fma4(acc[r], o.x, w0); fma4(acc[r], o.y, w1);
                fma4(acc[r], o.z, w2); fma4(acc[r], o.w, w3);
            }
        }
        #pragma unroll
        for (int r = 0; r < RPB; ++r) P4[(r * 4 + kg) * 128 + c4] = acc[r];
    }
    __syncthreads();
    // ---- stage 1r: reduce 4 kg partials + bias + relu -> s_feat ----
    {
        const int rr = tid >> 7, cc = tid & 127;
        float4 p0 = P4[(rr * 4 + 0) * 128 + cc];
        float4 p1 = P4[(rr * 4 + 1) * 128 + cc];
        float4 p2 = P4[(rr * 4 + 2) * 128 + cc];
        float4 p3 = P4[(rr * 4 + 3) * 128 + cc];
        float4 bb = *(const float4*)&b1[cc * 4];
        float4 v;
        v.x = fmaxf(p0.x + p1.x + p2.x + p3.x + bb.x, 0.f);
        v.y = fmaxf(p0.y + p1.y + p2.y + p3.y + bb.y, 0.f);
        v.z = fmaxf(p0.z + p1.z + p2.z + p3.z + bb.z, 0.f);
        v.w = fmaxf(p0.w + p1.w + p2.w + p3.w + bb.w, 0.f);
        *(float4*)&s_feat[rr][cc * 4] = v;
    }
    __syncthreads();   // P4 reads done before stage 2 overwrites s_scr

    // ---- stage 2a: h_term partials; thread = (g wave-uniform, c); 4-way m-split ----
    {
        const int c = tid & (CTX - 1);
        const int g = tid >> 7;              // m-range [g*64, g*64+64)
        const float* WcT = ws + WCT_OFF;
        float acc[RPB] = {0.f, 0.f, 0.f, 0.f};
        const float* wp = &WcT[c];
        #pragma unroll 2
        for (int m4 = 0; m4 < 16; ++m4) {
            int m = g * 64 + m4 * 4;
            float4 h0 = *(const float4*)&s_h[0][m];
            float4 h1 = *(const float4*)&s_h[1][m];
            float4 h2 = *(const float4*)&s_h[2][m];
            float4 h3 = *(const float4*)&s_h[3][m];
            float w0 = wp[(m + 0) * CTX];
            float w1 = wp[(m + 1) * CTX];
            float w2 = wp[(m + 2) * CTX];
            float w3 = wp[(m + 3) * CTX];
            acc[0] = fmaf(h0.x, w0, acc[0]); acc[0] = fmaf(h0.y, w1, acc[0]);
            acc[0] = fmaf(h0.z, w2, acc[0]); acc[0] = fmaf(h0.w, w3, acc[0]);
            acc[1] = fmaf(h1.x, w0, acc[1]); acc[1] = fmaf(h1.y, w1, acc[1]);
            acc[1] = fmaf(h1.z, w2, acc[1]); acc[1] = fmaf(h1.w, w3, acc[1]);
            acc[2] = fmaf(h2.x, w0, acc[2]); acc[2] = fmaf(h2.y, w1, acc[2]);
            acc[2] = fmaf(h2.z, w2, acc[2]); acc[2] = fmaf(h2.w, w3, acc[2]);
            acc[3] = fmaf(h3.x, w0, acc[3]); acc[3] = fmaf(h3.y, w1, acc[3]);
            acc[3] = fmaf(h3.z, w2, acc[3]); acc[3] = fmaf(h3.w, w3, acc[3]);
        }
        #pragma unroll
        for (int r = 0; r < RPB; ++r) s_buf[r][g * CTX + c] = acc[r];
    }
    __syncthreads();
    if (tid < CTX) {
        #pragma unroll
        for (int r = 0; r < RPB; ++r)
            s_hterm[r][tid] = K2LE * (bc[tid] + s_buf[r][tid] + s_buf[r][CTX + tid]
                            + s_buf[r][2 * CTX + tid] + s_buf[r][3 * CTX + tid]);
    }
    __syncthreads();

    // ---- stage 3: alog[r][o] = ba + Swa - sum_c (2wa_c)/(1 + 2^(ob*wc0s + hts)) ----
    {
        const float ba0 = ba[0];
        const int o = tid;
        float ob[RPB], acc[RPB];
        #pragma unroll
        for (int r = 0; r < RPB; ++r) { ob[r] = s_obs[r][o]; acc[r] = 0.0f; }
        float swa = 0.f;
        for (int c = 0; c < CTX; c += 4) {
            float4 v = *(const float4*)&s_wa2[c];
            swa += v.x + v.y + v.z + v.w;
        }
        swa *= 0.5f;
        #define TANH_TERM(r, hv, comp) { \
            float t_ = fmaf(ob[r], wc.comp, hv.comp); \
            float rc_ = RCPF(EXP2F(t_) + 1.0f); \
            acc[r] = fmaf(wa.comp, rc_, acc[r]); }
        for (int c4 = 0; c4 < CTX / 4; ++c4) {
            float4 wc = *(const float4*)&s_wc0[c4 * 4];
            float4 wa = *(const float4*)&s_wa2[c4 * 4];
            float4 h0 = *(const float4*)&s_hterm[0][c4 * 4];
            float4 h1 = *(const float4*)&s_hterm[1][c4 * 4];
            float4 h2 = *(const float4*)&s_hterm[2][c4 * 4];
            float4 h3 = *(const float4*)&s_hterm[3][c4 * 4];
            TANH_TERM(0, h0, x) TANH_TERM(0, h0, y) TANH_TERM(0, h0, z) TANH_TERM(0, h0, w)
            TANH_TERM(1, h1, x) TANH_TERM(1, h1, y) TANH_TERM(1, h1, z) TANH_TERM(1, h1, w)
            TANH_TERM(2, h2, x) TANH_TERM(2, h2, y) TANH_TERM(2, h2, z) TANH_TERM(2, h2, w)
            TANH_TERM(3, h3, x) TANH_TERM(3, h3, y) TANH_TERM(3, h3, z) TANH_TERM(3, h3, w)
        }
        #pragma unroll
        for (int r = 0; r < RPB; ++r) s_buf[r][o] = ba0 + swa - acc[r];
    }
    __syncthreads();

    // ---- stage 4: softmax over o + dset -> x[r] (wave per row) ----
    {
        const int w = tid >> 6, lane = tid & 63;
        if (w < RPB) {
            const int r = w;
            float m = -1e30f;
            for (int o = lane; o < OBS; o += 64) m = fmaxf(m, s_buf[r][o]);
            #pragma unroll
            for (int d = 32; d >= 1; d >>= 1) m = fmaxf(m, __shfl_xor(m, d));
            float se = 0.0f, sw = 0.0f;
            for (int o = lane; o < OBS; o += 64) {
                float e = __expf(s_buf[r][o] - m);
                se += e; sw += e * s_obs[r][o];
            }
            #pragma unroll
            for (int d = 32; d >= 1; d >>= 1) { se += __shfl_xor(se, d); sw += __shfl_xor(sw, d); }
            if (lane == 0) s_x[r] = sw / se;
        }
    }
    __syncthreads();

    // ---- stage 5a: GRU matvec partials; thread = (j, mg wave-uniform); 4 rows ----
    {
        const int j  = tid & (HM - 1);
        const int mg = tid >> 8;             // 0/1, wave-uniform
        const float4* __restrict__ Q = (const float4*)(ws + WHHQ_OFF); // [256][256]
        float accr[RPB] = {0,0,0,0}, accz[RPB] = {0,0,0,0}, accn[RPB] = {0,0,0,0};
        #pragma unroll 2
        for (int m4 = 0; m4 < 32; ++m4) {
            const int m = mg * 128 + m4 * 4;
            float4 q0 = Q[(m + 0) * HM + j];
            float4 q1 = Q[(m + 1) * HM + j];
            float4 q2 = Q[(m + 2) * HM + j];
            float4 q3 = Q[(m + 3) * HM + j];
            #pragma unroll
            for (int r = 0; r < RPB; ++r) {
                float4 h = *(const float4*)&s_h[r][m];   // wave-uniform broadcast
                accr[r] = fmaf(h.x, q0.x, accr[r]); accz[r] = fmaf(h.x, q0.y, accz[r]); accn[r] = fmaf(h.x, q0.z, accn[r]);
                accr[r] = fmaf(h.y, q1.x, accr[r]); accz[r] = fmaf(h.y, q1.y, accz[r]); accn[r] = fmaf(h.y, q1.z, accn[r]);
                accr[r] = fmaf(h.z, q2.x, accr[r]); accz[r] = fmaf(h.z, q2.y, accz[r]); accn[r] = fmaf(h.z, q2.z, accn[r]);
                accr[r] = fmaf(h.w, q3.x, accr[r]); accz[r] = fmaf(h.w, q3.y, accz[r]); accn[r] = fmaf(h.w, q3.z, accn[r]);
            }
        }
        // GP[mg][slot][j], slot = gate*4 + r ; stride-1 across lanes
        #pragma unroll
        for (int r = 0; r < RPB; ++r) {
            GP[(mg * 12 + 0 + r) * HM + j] = accr[r];
            GP[(mg * 12 + 4 + r) * HM + j] = accz[r];
            GP[(mg * 12 + 8 + r) * HM + j] = accn[r];
        }
    }
    __syncthreads();
    // ---- stage 5f: gate nonlinearities; thread = (j, row-pair) ----
    {
        const int j  = tid & (HM - 1);
        const int rp = tid >> 8;             // rows 2rp, 2rp+1
        float wih_r = W_ih[j], wih_z = W_ih[HM + j], wih_n = W_ih[2 * HM + j];
        float bih_r = b_ih[j], bih_z = b_ih[HM + j], bih_n = b_ih[2 * HM + j];
        float bhr = b_hh[j], bhz = b_hh[HM + j], bhn = b_hh[2 * HM + j];
        #pragma unroll
        for (int q = 0; q < 2; ++q) {
            const int r = rp * 2 + q;
            float ar = GP[(0 + r) * HM + j]  + GP[(12 + 0 + r) * HM + j]  + bhr;
            float az = GP[(4 + r) * HM + j]  + GP[(12 + 4 + r) * HM + j]  + bhz;
            float an = GP[(8 + r) * HM + j]  + GP[(12 + 8 + r) * HM + j]  + bhn;
            float x  = s_x[r];
            float hp = s_h[r][j];
            float rg = fast_sig(fmaf(x, wih_r, bih_r) + ar);
            float zg = fast_sig(fmaf(x, wih_z, bih_z) + az);
            float ng = fast_tanh(fmaf(x, wih_n, bih_n) + rg * an);
            s_h[r][j] = (1.0f - zg) * ng + zg * hp;   // own element only: no race
        }
    }
    __syncthreads();

    // ---- stage 6a: out2 partials; thread = (kg wave-uniform, c4); k-range 192 ----
    {
        const int kg = tid >> 7;
        const int c4 = tid & 127;
        const float4* __restrict__ W24 = (const float4*)(ws + W2T_OFF); // [768][128]
        float4 acc[RPB];
        #pragma unroll
        for (int r = 0; r < RPB; ++r) acc[r] = make_float4(0.f, 0.f, 0.f, 0.f);
        const int k0 = kg * 192, k1 = k0 + 192;
        const int kfe = (k1 < 512) ? k1 : 512;
        #pragma unroll 2
        for (int k = k0; k < kfe; k += 4) {          // feat part (wave-uniform bounds)
            float4 w0 = W24[(k + 0) * 128 + c4];
            float4 w1 = W24[(k + 1) * 128 + c4];
            float4 w2 = W24[(k + 2) * 128 + c4];
            float4 w3 = W24[(k + 3) * 128 + c4];
            #pragma unroll
            for (int r = 0; r < RPB; ++r) {
                float4 o = *(const float4*)&s_feat[r][k];
                fma4(acc[r], o.x, w0); fma4(acc[r], o.y, w1);
                fma4(acc[r], o.z, w2); fma4(acc[r], o.w, w3);
            }
        }
        const int khs = (k0 > 512) ? k0 : 512;
        #pragma unroll 2
        for (int k = khs; k < k1; k += 4) {          // hnew part
            float4 w0 = W24[(k + 0) * 128 + c4];
            float4 w1 = W24[(k + 1) * 128 + c4];
            float4 w2 = W24[(k + 2) * 128 + c4];
            float4 w3 = W24[(k + 3) * 128 + c4];
            #pragma unroll
            for (int r = 0; r < RPB; ++r) {
                float4 o = *(const float4*)&s_h[r][k - 512];
                fma4(acc[r], o.x, w0); fma4(acc[r], o.y, w1);
                fma4(acc[r], o.z, w2); fma4(acc[r], o.w, w3);
            }
        }
        #pragma unroll
        for (int r = 0; r < RPB; ++r) P4[(r * 4 + kg) * 128 + c4] = acc[r];
    }
    __syncthreads();
    // ---- stage 6r: reduce + bias + relu -> overwrite s_feat with out2 ----
    {
        const int rr = tid >> 7, cc = tid & 127;
        float4 p0 = P4[(rr * 4 + 0) * 128 + cc];
        float4 p1 = P4[(rr * 4 + 1) * 128 + cc];
        float4 p2 = P4[(rr * 4 + 2) * 128 + cc];
        float4 p3 = P4[(rr * 4 + 3) * 128 + cc];
        float4 bb = *(const float4*)&b2[cc * 4];
        float4 v;
        v.x = fmaxf(p0.x + p1.x + p2.x + p3.x + bb.x, 0.f);
        v.y = fmaxf(p0.y + p1.y + p2.y + p3.y + bb.y, 0.f);
        v.z = fmaxf(p0.z + p1.z + p2.z + p3.z + bb.z, 0.f);
        v.w = fmaxf(p0.w + p1.w + p2.w + p3.w + bb.w, 0.f);
        *(float4*)&s_feat[rr][cc * 4] = v;
    }
    __syncthreads();

    // ---- stage 7: heads + categorical sampling ----
    {
        const int w = tid >> 6, lane = tid & 63;
        if (w < RPB) {
            const int r = w;
            const int grow = row0 + r;
            float4 x0 = *(const float4*)&s_feat[r][lane * 8];
            float4 x1 = *(const float4*)&s_feat[r][lane * 8 + 4];
            float la[ACT];
            #pragma unroll
            for (int a = 0; a < ACT; ++a) {
                const float4* wa4 = (const float4*)&Wact[a * HS2 + lane * 8];
                float4 w0 = wa4[0], w1 = wa4[1];
                float p = x0.x * w0.x + x0.y * w0.y + x0.z * w0.z + x0.w * w0.w
                        + x1.x * w1.x + x1.y * w1.y + x1.z * w1.z + x1.w * w1.w;
                #pragma unroll
                for (int d = 32; d >= 1; d >>= 1) p += __shfl_xor(p, d);
                la[a] = p + bact[a];
            }
            float g = (lane < ACT) ? gumbel_ra(grow, lane) : 0.0f;
            float best = -1e30f; int amax = 0;
            float mx = -1e30f;
            #pragma unroll
            for (int a = 0; a < ACT; ++a) {
                float g_ = __shfl(g, a);
                float y = la[a] + g_;
                if (y > best) { best = y; amax = a; }
                mx = fmaxf(mx, la[a]);
            }
            float se = 0.0f;
            #pragma unroll
            for (int a = 0; a < ACT; ++a) se += __expf(la[a] - mx);
            float lse = mx + logf(se);
            float lp = la[amax] - lse;
            if (lane == 0) {
                out[grow]          = (float)amax;
                out[2 * NW + grow] = lp;
            }
        } else {
            const int r = w - RPB;
            const int grow = row0 + r;
            float4 x0 = *(const float4*)&s_feat[r][lane * 8];
            float4 x1 = *(const float4*)&s_feat[r][lane * 8 + 4];
            const float4* wc4 = (const float4*)&Wcrit[lane * 8];
            float4 w0 = wc4[0], w1 = wc4[1];
            float p = x0.x * w0.x + x0.y * w0.y + x0.z * w0.z + x0.w * w0.w
                    + x1.x * w1.x + x1.y * w1.y + x1.z * w1.z + x1.w * w1.w;
            #pragma unroll
            for (int d = 32; d >= 1; d >>= 1) p += __shfl_xor(p, d);
            if (lane == 0) out[NW + grow] = p + bcrit[0];
        }
    }
}

extern "C" void kernel_launch(void* const* d_in, const int* in_sizes, int n_in,
                              void* d_out, int out_size, void* d_ws, size_t ws_size,
                              hipStream_t stream) {
    const float* obs   = (const float*)d_in[0];
    const float* hmem  = (const float*)d_in[1];
    const float* W1    = (const float*)d_in[2];
    const float* b1    = (const float*)d_in[3];
    const float* Wc    = (const float*)d_in[4];
    const float* bc    = (const float*)d_in[5];
    const float* Wa    = (const float*)d_in[6];
    const float* ba    = (const float*)d_in[7];
    const float* W_ih  = (const float*)d_in[8];
    const float* b_ih  = (const float*)d_in[9];
    const float* W_hh  = (const float*)d_in[10];
    const float* b_hh  = (const float*)d_in[11];
    const float* W2    = (const float*)d_in[12];
    const float* b2    = (const float*)d_in[13];
    const float* Wact  = (const float*)d_in[14];
    const float* bact  = (const float*)d_in[15];
    const float* Wcrit = (const float*)d_in[16];
    const float* bcrit = (const float*)d_in[17];
    float* ws = (float*)d_ws;

    transpose_weights<<<736, 256, 0, stream>>>(W1, Wc, W_hh, W2, ws);

    iamgru_policy_kernel<<<NW / RPB, T, 0, stream>>>(
        obs, hmem, b1, Wc, bc, Wa, ba, W_ih, b_ih, b_hh,
        b2, Wact, bact, Wcrit, bcrit, ws, (float*)d_out);
}